// Round 6
// baseline (598.921 us; speedup 1.0000x reference)
//
#include <hip/hip_runtime.h>
#include <stdint.h>

typedef float f32x4 __attribute__((ext_vector_type(4)));

// One WAVE per 32-bit word (R2 structure) with SELECTIVE cache policy:
//   a_bytes : nontemporal loads  -> pure sequential DRAM read stream, no L3 alloc
//   b_bytes : cached loads       -> 268 MB ~fits the 256 MB L3 alone, so
//                                   cross-iteration residency ~95% (vs ~50% when
//                                   both inputs competed), misses are thin
//   out     : nontemporal stores -> write stream must not evict b's residency
// This keeps R5's sequential-DRAM efficiency while cutting ~250 MB of traffic.
// Lane l's chunk k is the float4 at word_base + k*256 + l*4 floats: every
// load/store instruction is a contiguous aligned 1 KiB across the 64 lanes.
// No LDS, no barriers, no shuffles; word arithmetic is SALU via __ballot.
__global__ __launch_bounds__(256) void vm_kernel(
    const float* __restrict__ a_bytes,
    const float* __restrict__ b_bytes,
    float* __restrict__ out,
    int n_words)
{
    const int lane = threadIdx.x & 63;
    const int w    = blockIdx.x * 4 + (threadIdx.x >> 6);
    if (w >= n_words) return;

    const long base = (long)w * 1024 + lane * 4;
    const float* pa = a_bytes + base;
    const float* pb = b_bytes + base;

    // Issue all 8 loads up front (independent, 1 KiB/instr coalesced).
    const f32x4 a0 = __builtin_nontemporal_load((const f32x4*)(pa));
    const f32x4 a1 = __builtin_nontemporal_load((const f32x4*)(pa + 256));
    const f32x4 a2 = __builtin_nontemporal_load((const f32x4*)(pa + 512));
    const f32x4 a3 = __builtin_nontemporal_load((const f32x4*)(pa + 768));
    const f32x4 b0 = *(const f32x4*)(pb);
    const f32x4 b1 = *(const f32x4*)(pb + 256);
    const f32x4 b2 = *(const f32x4*)(pb + 512);
    const f32x4 b3 = *(const f32x4*)(pb + 768);

    // Index of the single 1.0 within a 256-float chunk, via 4 ballots.
    // Exactly one mask is nonzero; index = 4*lane_of_hit + component.
    auto idx_of = [&](const f32x4 v) -> uint32_t {
        const uint64_t m0 = __ballot(v.x > 0.5f);
        const uint64_t m1 = __ballot(v.y > 0.5f);
        const uint64_t m2 = __ballot(v.z > 0.5f);
        const uint64_t m3 = __ballot(v.w > 0.5f);
        const uint64_t m  = m0 | m1 | m2 | m3;
        const uint32_t hl = (uint32_t)__ffsll((unsigned long long)m) - 1u;
        const uint32_t c  = (m1 ? 1u : 0u) | (m2 ? 2u : 0u) | (m3 ? 3u : 0u);
        return hl * 4u + c;
    };

    const uint32_t aw = idx_of(a0) | (idx_of(a1) << 8) |
                        (idx_of(a2) << 16) | (idx_of(a3) << 24);
    const uint32_t bw = idx_of(b0) | (idx_of(b1) << 8) |
                        (idx_of(b2) << 16) | (idx_of(b3) << 24);

    const uint32_t s = aw + bw;   // ripple-carry add; carry out of byte 3 dropped
    const uint32_t o = s ^ aw;    // chained per-byte XOR with operand a

    float* po = out + base;
    const int j = lane * 4;
#pragma unroll
    for (int k = 0; k < 4; ++k) {
        const int oi = (int)((o >> (8 * k)) & 255u);
        f32x4 ov;
        ov.x = (j     == oi) ? 1.0f : 0.0f;
        ov.y = (j + 1 == oi) ? 1.0f : 0.0f;
        ov.z = (j + 2 == oi) ? 1.0f : 0.0f;
        ov.w = (j + 3 == oi) ? 1.0f : 0.0f;
        __builtin_nontemporal_store(ov, (f32x4*)(po + k * 256));
    }
}

extern "C" void kernel_launch(void* const* d_in, const int* in_sizes, int n_in,
                              void* d_out, int out_size, void* d_ws, size_t ws_size,
                              hipStream_t stream)
{
    const float* a_bytes = (const float*)d_in[0];  // [B,4,256]
    const float* b_bytes = (const float*)d_in[1];  // [B,4,256]
    float* out = (float*)d_out;                    // [B,4,256]
    const int n_words = in_sizes[0] / 1024;        // B

    const int blocks = (n_words + 3) / 4;          // one wave (64 thr) per word
    vm_kernel<<<blocks, 256, 0, stream>>>(a_bytes, b_bytes, out, n_words);
}

// Round 7
// 580.063 us; speedup vs baseline: 1.0325x; 1.0325x over previous
//
#include <hip/hip_runtime.h>
#include <stdint.h>

typedef float f32x4 __attribute__((ext_vector_type(4)));

// One WAVE per 32-bit word. Cache policy (single-variable change from R5):
//   loads  : nontemporal (both inputs) -> pure sequential DRAM read streams,
//            no L3 allocation (R5/R6 proved L3 read-residency has NEGATIVE
//            value here: the half-resident miss pattern throttles DRAM to
//            ~3 TB/s, and even a 100%-resident input is slower than streaming)
//   stores : NORMAL (cached) -> let TCC write-combine full lines and write
//            back lazily, like the 6.5 TB/s fillBuffer reference; NT stores
//            stream direct to DRAM and may fight the concurrent read stream.
// Lane l's chunk k is the float4 at word_base + k*256 + l*4 floats: every
// load/store instruction is a contiguous aligned 1 KiB across the 64 lanes.
// No LDS, no barriers, no shuffles; word arithmetic is SALU via __ballot.
__global__ __launch_bounds__(256) void vm_kernel(
    const float* __restrict__ a_bytes,
    const float* __restrict__ b_bytes,
    float* __restrict__ out,
    int n_words)
{
    const int lane = threadIdx.x & 63;
    const int w    = blockIdx.x * 4 + (threadIdx.x >> 6);
    if (w >= n_words) return;

    const long base = (long)w * 1024 + lane * 4;
    const float* pa = a_bytes + base;
    const float* pb = b_bytes + base;

    // Issue all 8 loads up front (independent, 1 KiB/instr coalesced), NT.
    const f32x4 a0 = __builtin_nontemporal_load((const f32x4*)(pa));
    const f32x4 a1 = __builtin_nontemporal_load((const f32x4*)(pa + 256));
    const f32x4 a2 = __builtin_nontemporal_load((const f32x4*)(pa + 512));
    const f32x4 a3 = __builtin_nontemporal_load((const f32x4*)(pa + 768));
    const f32x4 b0 = __builtin_nontemporal_load((const f32x4*)(pb));
    const f32x4 b1 = __builtin_nontemporal_load((const f32x4*)(pb + 256));
    const f32x4 b2 = __builtin_nontemporal_load((const f32x4*)(pb + 512));
    const f32x4 b3 = __builtin_nontemporal_load((const f32x4*)(pb + 768));

    // Index of the single 1.0 within a 256-float chunk, via 4 ballots.
    // Exactly one mask is nonzero; index = 4*lane_of_hit + component.
    auto idx_of = [&](const f32x4 v) -> uint32_t {
        const uint64_t m0 = __ballot(v.x > 0.5f);
        const uint64_t m1 = __ballot(v.y > 0.5f);
        const uint64_t m2 = __ballot(v.z > 0.5f);
        const uint64_t m3 = __ballot(v.w > 0.5f);
        const uint64_t m  = m0 | m1 | m2 | m3;
        const uint32_t hl = (uint32_t)__ffsll((unsigned long long)m) - 1u;
        const uint32_t c  = (m1 ? 1u : 0u) | (m2 ? 2u : 0u) | (m3 ? 3u : 0u);
        return hl * 4u + c;
    };

    const uint32_t aw = idx_of(a0) | (idx_of(a1) << 8) |
                        (idx_of(a2) << 16) | (idx_of(a3) << 24);
    const uint32_t bw = idx_of(b0) | (idx_of(b1) << 8) |
                        (idx_of(b2) << 16) | (idx_of(b3) << 24);

    const uint32_t s = aw + bw;   // ripple-carry add; carry out of byte 3 dropped
    const uint32_t o = s ^ aw;    // chained per-byte XOR with operand a

    float* po = out + base;
    const int j = lane * 4;
#pragma unroll
    for (int k = 0; k < 4; ++k) {
        const int oi = (int)((o >> (8 * k)) & 255u);
        f32x4 ov;
        ov.x = (j     == oi) ? 1.0f : 0.0f;
        ov.y = (j + 1 == oi) ? 1.0f : 0.0f;
        ov.z = (j + 2 == oi) ? 1.0f : 0.0f;
        ov.w = (j + 3 == oi) ? 1.0f : 0.0f;
        *(f32x4*)(po + k * 256) = ov;   // normal (cached) store
    }
}

extern "C" void kernel_launch(void* const* d_in, const int* in_sizes, int n_in,
                              void* d_out, int out_size, void* d_ws, size_t ws_size,
                              hipStream_t stream)
{
    const float* a_bytes = (const float*)d_in[0];  // [B,4,256]
    const float* b_bytes = (const float*)d_in[1];  // [B,4,256]
    float* out = (float*)d_out;                    // [B,4,256]
    const int n_words = in_sizes[0] / 1024;        // B

    const int blocks = (n_words + 3) / 4;          // one wave (64 thr) per word
    vm_kernel<<<blocks, 256, 0, stream>>>(a_bytes, b_bytes, out, n_words);
}

// Round 8
// 567.065 us; speedup vs baseline: 1.0562x; 1.0229x over previous
//
#include <hip/hip_runtime.h>
#include <stdint.h>

typedef float f32x4 __attribute__((ext_vector_type(4)));

// Two-phase structure, each phase a PURE stream (the two proven wins combined):
//   Phase 1: NT loads of both inputs (sequential uncached DRAM read, 537 MB),
//            ballot index extraction, SALU word math, 4 B/word result to ws
//            (0.26 MB — noise). No write stream competing with reads.
//   Phase 2: 4 B/word wave-uniform read (L2-hot from phase 1) -> 4 KiB one-hot
//            cached stores. Pure write stream, same pattern as the 6.55 TB/s
//            fillBuffer reference.
// R4 tried this split with CACHED loads and lost to the scattered-miss DRAM
// pattern; R5 proved NT sequential reads fix that. This is the untried cell.
// Lane l's chunk k is the float4 at word_base + k*256 + l*4 floats: every
// load/store instruction is a contiguous aligned 1 KiB across the 64 lanes.

__global__ __launch_bounds__(256) void vm_phase1(
    const float* __restrict__ a_bytes,
    const float* __restrict__ b_bytes,
    uint32_t* __restrict__ ws,
    int n_words)
{
    const int lane = threadIdx.x & 63;
    const int w    = blockIdx.x * 4 + (threadIdx.x >> 6);
    if (w >= n_words) return;

    const long base = (long)w * 1024 + lane * 4;
    const float* pa = a_bytes + base;
    const float* pb = b_bytes + base;

    const f32x4 a0 = __builtin_nontemporal_load((const f32x4*)(pa));
    const f32x4 a1 = __builtin_nontemporal_load((const f32x4*)(pa + 256));
    const f32x4 a2 = __builtin_nontemporal_load((const f32x4*)(pa + 512));
    const f32x4 a3 = __builtin_nontemporal_load((const f32x4*)(pa + 768));
    const f32x4 b0 = __builtin_nontemporal_load((const f32x4*)(pb));
    const f32x4 b1 = __builtin_nontemporal_load((const f32x4*)(pb + 256));
    const f32x4 b2 = __builtin_nontemporal_load((const f32x4*)(pb + 512));
    const f32x4 b3 = __builtin_nontemporal_load((const f32x4*)(pb + 768));

    auto idx_of = [&](const f32x4 v) -> uint32_t {
        const uint64_t m0 = __ballot(v.x > 0.5f);
        const uint64_t m1 = __ballot(v.y > 0.5f);
        const uint64_t m2 = __ballot(v.z > 0.5f);
        const uint64_t m3 = __ballot(v.w > 0.5f);
        const uint64_t m  = m0 | m1 | m2 | m3;
        const uint32_t hl = (uint32_t)__ffsll((unsigned long long)m) - 1u;
        const uint32_t c  = (m1 ? 1u : 0u) | (m2 ? 2u : 0u) | (m3 ? 3u : 0u);
        return hl * 4u + c;
    };

    const uint32_t aw = idx_of(a0) | (idx_of(a1) << 8) |
                        (idx_of(a2) << 16) | (idx_of(a3) << 24);
    const uint32_t bw = idx_of(b0) | (idx_of(b1) << 8) |
                        (idx_of(b2) << 16) | (idx_of(b3) << 24);
    const uint32_t s = aw + bw;   // ripple-carry add; carry out of byte 3 dropped
    const uint32_t o = s ^ aw;    // chained per-byte XOR with operand a

    if (lane == 0) ws[w] = o;
}

__global__ __launch_bounds__(256) void vm_phase2(
    const uint32_t* __restrict__ ws,
    float* __restrict__ out,
    int n_words)
{
    const int lane = threadIdx.x & 63;
    const int w    = blockIdx.x * 4 + (threadIdx.x >> 6);
    if (w >= n_words) return;

    const uint32_t o = ws[w];            // wave-uniform -> scalar load, L2-hot
    float* po = out + (long)w * 1024 + lane * 4;
    const int j = lane * 4;
#pragma unroll
    for (int k = 0; k < 4; ++k) {
        const int oi = (int)((o >> (8 * k)) & 255u);
        f32x4 ov;
        ov.x = (j     == oi) ? 1.0f : 0.0f;
        ov.y = (j + 1 == oi) ? 1.0f : 0.0f;
        ov.z = (j + 2 == oi) ? 1.0f : 0.0f;
        ov.w = (j + 3 == oi) ? 1.0f : 0.0f;
        *(f32x4*)(po + k * 256) = ov;    // cached store, fill-kernel pattern
    }
}

// Fallback: fused all-NT single pass (R5 — best fused variant) if ws too small.
__global__ __launch_bounds__(256) void vm_fused(
    const float* __restrict__ a_bytes,
    const float* __restrict__ b_bytes,
    float* __restrict__ out,
    int n_words)
{
    const int lane = threadIdx.x & 63;
    const int w    = blockIdx.x * 4 + (threadIdx.x >> 6);
    if (w >= n_words) return;

    const long base = (long)w * 1024 + lane * 4;
    const float* pa = a_bytes + base;
    const float* pb = b_bytes + base;

    const f32x4 a0 = __builtin_nontemporal_load((const f32x4*)(pa));
    const f32x4 a1 = __builtin_nontemporal_load((const f32x4*)(pa + 256));
    const f32x4 a2 = __builtin_nontemporal_load((const f32x4*)(pa + 512));
    const f32x4 a3 = __builtin_nontemporal_load((const f32x4*)(pa + 768));
    const f32x4 b0 = __builtin_nontemporal_load((const f32x4*)(pb));
    const f32x4 b1 = __builtin_nontemporal_load((const f32x4*)(pb + 256));
    const f32x4 b2 = __builtin_nontemporal_load((const f32x4*)(pb + 512));
    const f32x4 b3 = __builtin_nontemporal_load((const f32x4*)(pb + 768));

    auto idx_of = [&](const f32x4 v) -> uint32_t {
        const uint64_t m0 = __ballot(v.x > 0.5f);
        const uint64_t m1 = __ballot(v.y > 0.5f);
        const uint64_t m2 = __ballot(v.z > 0.5f);
        const uint64_t m3 = __ballot(v.w > 0.5f);
        const uint64_t m  = m0 | m1 | m2 | m3;
        const uint32_t hl = (uint32_t)__ffsll((unsigned long long)m) - 1u;
        const uint32_t c  = (m1 ? 1u : 0u) | (m2 ? 2u : 0u) | (m3 ? 3u : 0u);
        return hl * 4u + c;
    };

    const uint32_t aw = idx_of(a0) | (idx_of(a1) << 8) |
                        (idx_of(a2) << 16) | (idx_of(a3) << 24);
    const uint32_t bw = idx_of(b0) | (idx_of(b1) << 8) |
                        (idx_of(b2) << 16) | (idx_of(b3) << 24);
    const uint32_t s = aw + bw;
    const uint32_t o = s ^ aw;

    float* po = out + base;
    const int j = lane * 4;
#pragma unroll
    for (int k = 0; k < 4; ++k) {
        const int oi = (int)((o >> (8 * k)) & 255u);
        f32x4 ov;
        ov.x = (j     == oi) ? 1.0f : 0.0f;
        ov.y = (j + 1 == oi) ? 1.0f : 0.0f;
        ov.z = (j + 2 == oi) ? 1.0f : 0.0f;
        ov.w = (j + 3 == oi) ? 1.0f : 0.0f;
        __builtin_nontemporal_store(ov, (f32x4*)(po + k * 256));
    }
}

extern "C" void kernel_launch(void* const* d_in, const int* in_sizes, int n_in,
                              void* d_out, int out_size, void* d_ws, size_t ws_size,
                              hipStream_t stream)
{
    const float* a_bytes = (const float*)d_in[0];  // [B,4,256]
    const float* b_bytes = (const float*)d_in[1];  // [B,4,256]
    float* out = (float*)d_out;                    // [B,4,256]
    const int n_words = in_sizes[0] / 1024;        // B
    const int blocks  = (n_words + 3) / 4;         // 4 waves/block, 1 word/wave

    if (d_ws != nullptr && ws_size >= (size_t)n_words * 4) {
        uint32_t* ws = (uint32_t*)d_ws;
        vm_phase1<<<blocks, 256, 0, stream>>>(a_bytes, b_bytes, ws, n_words);
        vm_phase2<<<blocks, 256, 0, stream>>>(ws, out, n_words);
    } else {
        vm_fused<<<blocks, 256, 0, stream>>>(a_bytes, b_bytes, out, n_words);
    }
}